// Round 13
// baseline (606.045 us; speedup 1.0000x reference)
//
#include <hip/hip_runtime.h>

#define N_NODES 50000
#define N_EDGES 1600000
#define R_REL 8
#define G_GRAPHS 64
#define D_INF 128
#define HIDF 128
#define CLSF 10

#define S_SEG (N_NODES * R_REL)   // 400000 (dst, rel) segments
#define KTOT 1152
#define KREL 1024
#define PCHUNK 16                 // pool stage-1 chunks per graph

#define XG 8                      // XCD groups for partitioned sort
#define NODES_PER_G (N_NODES / XG)      // 6250
#define SORT_BLKS_PER_G 256
#define SORT_GRID (XG * SORT_BLKS_PER_G)

typedef __attribute__((ext_vector_type(8))) short short8;
typedef __attribute__((ext_vector_type(4))) float floatx4;

typedef __attribute__((address_space(1))) const unsigned int guint;
typedef __attribute__((address_space(3))) unsigned int luint;
__device__ __forceinline__ void gload_lds16(const void* g, void* l) {
    // async global->LDS, 16 B/lane; LDS dest = wave-uniform base + lane*16
    __builtin_amdgcn_global_load_lds((guint*)g, (luint*)l, 16, 0, 0);
}

__device__ __forceinline__ unsigned short f2bf(float f) {
    unsigned int u = __float_as_uint(f);
    unsigned int r = (u + 0x7fffu + ((u >> 16) & 1u)) >> 16;   // RNE
    return (unsigned short)r;
}
__device__ __forceinline__ float bf2f(unsigned short h) {
    return __uint_as_float(((unsigned int)h) << 16);
}
// exact unpack of a packed bf16 pair (uint32) into two fp32
__device__ __forceinline__ float bflo(unsigned int u) { return __uint_as_float(u << 16); }
__device__ __forceinline__ float bfhi(unsigned int u) { return __uint_as_float(u & 0xffff0000u); }

// ---------------- count edges per (dst, rel) segment — XCD-partitioned --------
__global__ __launch_bounds__(256) void count_kernel(const int* __restrict__ dst,
                                                    const int* __restrict__ et,
                                                    int* __restrict__ cnt) {
    int xg = blockIdx.x & (XG - 1);
    int inner = blockIdx.x >> 3;
    int lo = xg * NODES_PER_G, hi = lo + NODES_PER_G;
    for (int e = inner * 256 + threadIdx.x; e < N_EDGES; e += SORT_BLKS_PER_G * 256) {
        int d = dst[e];
        if (d >= lo && d < hi) {
            atomicAdd(&cnt[d * R_REL + et[e]], 1);
        }
    }
}

// ---------------- two-level exclusive scan over segment counts ----------------
#define SCAN_BLK 256
#define SCAN_ELEMS 1024
#define NB_SCAN ((S_SEG + SCAN_ELEMS - 1) / SCAN_ELEMS)   // 391

__global__ __launch_bounds__(SCAN_BLK) void scan1_kernel(const int* __restrict__ cnt,
                                                         int* __restrict__ off,
                                                         int* __restrict__ bsum) {
    __shared__ int sd[SCAN_BLK];
    int t = threadIdx.x;
    int base = blockIdx.x * SCAN_ELEMS + t * 4;
    int v[4];
    int tsum = 0;
#pragma unroll
    for (int j = 0; j < 4; j++) {
        v[j] = (base + j < S_SEG) ? cnt[base + j] : 0;
        tsum += v[j];
    }
    sd[t] = tsum;
    __syncthreads();
    for (int d = 1; d < SCAN_BLK; d <<= 1) {
        int x = (t >= d) ? sd[t - d] : 0;
        __syncthreads();
        sd[t] += x;
        __syncthreads();
    }
    int incl = sd[t];
    int run = incl - tsum;
#pragma unroll
    for (int j = 0; j < 4; j++) {
        if (base + j < S_SEG) off[base + j] = run;
        run += v[j];
    }
    if (t == SCAN_BLK - 1) bsum[blockIdx.x] = incl;
}

__global__ __launch_bounds__(512) void scan2_kernel(int* __restrict__ bsum) {
    __shared__ int sd[512];
    int t = threadIdx.x;
    int v = (t < NB_SCAN) ? bsum[t] : 0;
    sd[t] = v;
    __syncthreads();
    for (int d = 1; d < 512; d <<= 1) {
        int x = (t >= d) ? sd[t - d] : 0;
        __syncthreads();
        sd[t] += x;
        __syncthreads();
    }
    if (t < NB_SCAN) bsum[t] = sd[t] - v;
}

// make off[] absolute (add block prefix)
__global__ void absoff_kernel(int* __restrict__ off, const int* __restrict__ bsum) {
    int i = blockIdx.x * blockDim.x + threadIdx.x;
    if (i < S_SEG) off[i] += bsum[i >> 10];
}

// ---------------- bin edges — XCD-partitioned, cursor pre-init to off ----------
__global__ __launch_bounds__(256) void bin_kernel(const int* __restrict__ src,
                                                  const int* __restrict__ dst,
                                                  const int* __restrict__ et,
                                                  int* __restrict__ cursor,
                                                  int* __restrict__ sorted_src) {
    int xg = blockIdx.x & (XG - 1);
    int inner = blockIdx.x >> 3;
    int lo = xg * NODES_PER_G, hi = lo + NODES_PER_G;
    for (int e = inner * 256 + threadIdx.x; e < N_EDGES; e += SORT_BLKS_PER_G * 256) {
        int d = dst[e];
        if (d >= lo && d < hi) {
            int seg = d * R_REL + et[e];
            int pos = atomicAdd(&cursor[seg], 1);    // absolute position
            sorted_src[pos] = src[e];
        }
    }
}

// ---------------- convert x fp32 -> bf16 compact [N,128] ----------------
__global__ void convx_kernel(const float* __restrict__ x, unsigned short* __restrict__ xb) {
    int idx = blockIdx.x * blockDim.x + threadIdx.x;
    if (idx < N_NODES * D_INF) xb[idx] = f2bf(x[idx]);
}

// ---------------- build transposed bf16 weights wt[128][1152]: [col][k] ----------
__global__ __launch_bounds__(256) void convw_kernel(const float* __restrict__ Wf,
                                                    const float* __restrict__ root,
                                                    unsigned short* __restrict__ wt) {
    __shared__ float t[16][17];
    int k0 = blockIdx.x * 16, c0 = blockIdx.y * 16;
    int tx = threadIdx.x & 15, ty = threadIdx.x >> 4;
    int k = k0 + ty, c = c0 + tx;
    float v = (k < KREL) ? Wf[(size_t)k * HIDF + c] : root[(size_t)(k - KREL) * HIDF + c];
    t[ty][tx] = v;
    __syncthreads();
    wt[(size_t)(c0 + ty) * KTOT + k0 + tx] = f2bf(t[tx][ty]);
}

// ---------------- gather-aggregate: ONE SEGMENT PER WAVE ----------------
// 64 lanes x 1 dword = one full 256 B feature row per load instruction.
// beg/n/idx are wave-uniform -> scalar loads + scalar row-base math; zero
// divergence. Accumulation order per channel identical to previous rounds.
__global__ __launch_bounds__(256) void agg_kernel(const unsigned short* __restrict__ feat,  // [N,128]
                                                  const int* __restrict__ sorted_src,
                                                  const int* __restrict__ off,    // absolute
                                                  const int* __restrict__ cnt,
                                                  unsigned short* __restrict__ meanb) { // [N,1024]
    int g = blockIdx.x * 4 + (threadIdx.x >> 6);   // one segment per wave
    int c = threadIdx.x & 63;                      // lane = 2 channels (one uint)
    int n = cnt[g];
    int beg = off[g];
    float a0 = 0.f, a1 = 0.f;
    int i = 0;
    for (; i + 4 <= n; i += 4) {
        int i0 = sorted_src[beg + i + 0];
        int i1 = sorted_src[beg + i + 1];
        int i2 = sorted_src[beg + i + 2];
        int i3 = sorted_src[beg + i + 3];
        unsigned int v0 = *(const unsigned int*)(feat + (size_t)i0 * HIDF + c * 2);
        unsigned int v1 = *(const unsigned int*)(feat + (size_t)i1 * HIDF + c * 2);
        unsigned int v2 = *(const unsigned int*)(feat + (size_t)i2 * HIDF + c * 2);
        unsigned int v3 = *(const unsigned int*)(feat + (size_t)i3 * HIDF + c * 2);
        a0 += bflo(v0) + bflo(v1) + bflo(v2) + bflo(v3);
        a1 += bfhi(v0) + bfhi(v1) + bfhi(v2) + bfhi(v3);
    }
    for (; i < n; i++) {
        int ii = sorted_src[beg + i];
        unsigned int v = *(const unsigned int*)(feat + (size_t)ii * HIDF + c * 2);
        a0 += bflo(v); a1 += bfhi(v);
    }
    float inv = 1.0f / (float)max(n, 1);
    unsigned int pk = (unsigned int)f2bf(a0 * inv) | ((unsigned int)f2bf(a1 * inv) << 16);
    int node = g >> 3, rel = g & 7;
    unsigned int* dstp = (unsigned int*)(meanb + (size_t)node * KREL + rel * HIDF + c * 2);
    __builtin_nontemporal_store(pk, dstp);
}

// ---------------- MFMA bf16 fused RGCN layer GEMM, M=128, async staging -------
__global__ __launch_bounds__(256) void gemm_mfma(
    const unsigned short* __restrict__ meanb,  // [N, 1024] bf16
    const unsigned short* __restrict__ hin,    // [N, 128] bf16
    const unsigned short* __restrict__ wt,     // [128, 1152] bf16 (transposed weights)
    const float* __restrict__ bias,            // [128] fp32
    unsigned short* __restrict__ hout)         // [N, 128] bf16
{
    __shared__ __align__(16) unsigned short Alds[128][32];
    __shared__ __align__(16) unsigned short Blds[128][32];

    const int tx = threadIdx.x;
    const int wave = tx >> 6, lane = tx & 63;
    const int quad = lane >> 4, lq = lane & 15;
    const int row0 = blockIdx.x * 128;

    floatx4 acc[2][8];
#pragma unroll
    for (int i = 0; i < 2; i++)
#pragma unroll
        for (int j = 0; j < 8; j++) acc[i][j] = (floatx4){0.f, 0.f, 0.f, 0.f};

    const int srow = lane >> 2;    // 0..15: row within 16-row group
    const int sch  = lane & 3;     // 16-B chunk within 64-B row

    for (int k0 = 0; k0 < KTOT; k0 += 32) {
        // ---- async stage A and B: per wave 2x16 rows, 1024 B per instruction ----
#pragma unroll
        for (int p = 0; p < 2; p++) {
            int rr = (wave * 2 + p) * 16 + srow;          // 0..127
            int gr = row0 + rr; if (gr >= N_NODES) gr = N_NODES - 1;   // clamp tail
            const unsigned short* ga = (k0 < KREL)
                ? meanb + (size_t)gr * KREL + k0 + sch * 8
                : hin + (size_t)gr * HIDF + (k0 - KREL) + sch * 8;
            gload_lds16(ga, &Alds[(wave * 2 + p) * 16][0]);
            const unsigned short* gb = wt + (size_t)rr * KTOT + k0 + sch * 8;
            gload_lds16(gb, &Blds[(wave * 2 + p) * 16][0]);
        }
        __syncthreads();

        short8 af[2], bfr[8];
#pragma unroll
        for (int i = 0; i < 2; i++)
            af[i] = *(const short8*)(&Alds[wave * 32 + i * 16 + lq][quad * 8]);
#pragma unroll
        for (int j = 0; j < 8; j++)
            bfr[j] = *(const short8*)(&Blds[j * 16 + lq][quad * 8]);
#pragma unroll
        for (int i = 0; i < 2; i++)
#pragma unroll
            for (int j = 0; j < 8; j++)
                acc[i][j] = __builtin_amdgcn_mfma_f32_16x16x32_bf16(af[i], bfr[j], acc[i][j], 0, 0, 0);
        __syncthreads();
    }

    // epilogue: C/D layout col=lane&15, row=quad*4+reg
#pragma unroll
    for (int i = 0; i < 2; i++) {
#pragma unroll
        for (int j = 0; j < 8; j++) {
            int col = j * 16 + lq;
            float b = bias[col];
#pragma unroll
            for (int r = 0; r < 4; r++) {
                int row = row0 + wave * 32 + i * 16 + quad * 4 + r;
                if (row < N_NODES) {
                    float v = fmaxf(acc[i][j][r] + b, 0.0f);
                    hout[(size_t)row * HIDF + col] = f2bf(v);
                }
            }
        }
    }
}

// ---------------- global mean pool, two-stage, no atomics ----------------
__global__ __launch_bounds__(256) void pool1_kernel(const unsigned short* __restrict__ h,
                                                    const int* __restrict__ batch,
                                                    float* __restrict__ partial) {  // [G][PCHUNK][128]
    int g = blockIdx.x;
    int p = blockIdx.y;
    int lo, hi;
    {
        int l = 0, r = N_NODES;
        while (l < r) { int m = (l + r) >> 1; if (batch[m] < g) l = m + 1; else r = m; }
        lo = l;
        l = lo; r = N_NODES;
        while (l < r) { int m = (l + r) >> 1; if (batch[m] < g + 1) l = m + 1; else r = m; }
        hi = l;
    }
    int t = threadIdx.x;
    int rowlane = t >> 5;
    int c4 = t & 31;
    float a0 = 0.f, a1 = 0.f, a2 = 0.f, a3 = 0.f;
    for (int n = lo + p + rowlane * PCHUNK; n < hi; n += 8 * PCHUNK) {
        uint2 v = *(const uint2*)(h + (size_t)n * HIDF + c4 * 4);
        a0 += bflo(v.x); a1 += bfhi(v.x); a2 += bflo(v.y); a3 += bfhi(v.y);
    }
    __shared__ float red[8][128];
    if (rowlane == 0) {
        red[0][c4 * 4 + 0] = a0; red[0][c4 * 4 + 1] = a1;
        red[0][c4 * 4 + 2] = a2; red[0][c4 * 4 + 3] = a3;
    }
    __syncthreads();
    for (int s = 1; s < 8; s++) {
        if (rowlane == s) {
            red[0][c4 * 4 + 0] += a0; red[0][c4 * 4 + 1] += a1;
            red[0][c4 * 4 + 2] += a2; red[0][c4 * 4 + 3] += a3;
        }
        __syncthreads();
    }
    if (t < 128) partial[((size_t)g * PCHUNK + p) * 128 + t] = red[0][t];
}

__global__ __launch_bounds__(128) void pool2_kernel(const float* __restrict__ partial,
                                                    const int* __restrict__ batch,
                                                    float* __restrict__ gmean) {
    int g = blockIdx.x;
    int lo, hi;
    {
        int l = 0, r = N_NODES;
        while (l < r) { int m = (l + r) >> 1; if (batch[m] < g) l = m + 1; else r = m; }
        lo = l;
        l = lo; r = N_NODES;
        while (l < r) { int m = (l + r) >> 1; if (batch[m] < g + 1) l = m + 1; else r = m; }
        hi = l;
    }
    int t = threadIdx.x;
    float s = 0.f;
#pragma unroll
    for (int p = 0; p < PCHUNK; p++)
        s += partial[((size_t)g * PCHUNK + p) * 128 + t];
    gmean[g * HIDF + t] = s / (float)max(hi - lo, 1);
}

// ---------------- final linear ----------------
__global__ void final_kernel(const float* __restrict__ gmean,
                             const float* __restrict__ lin_w,  // [128, 10]
                             const float* __restrict__ lin_b,  // [10]
                             float* __restrict__ out) {        // [64, 10]
    __shared__ float gl[HIDF];
    int g = blockIdx.x;
    int hh = threadIdx.x;
    gl[hh] = gmean[g * HIDF + hh];
    __syncthreads();
    if (hh < CLSF) {
        float s = lin_b[hh];
#pragma unroll 16
        for (int d = 0; d < HIDF; d++) s += gl[d] * lin_w[d * CLSF + hh];
        out[g * CLSF + hh] = s;
    }
}

extern "C" void kernel_launch(void* const* d_in, const int* in_sizes, int n_in,
                              void* d_out, int out_size, void* d_ws, size_t ws_size,
                              hipStream_t stream) {
    const float* x     = (const float*)d_in[0];
    const int*   ei    = (const int*)d_in[1];
    const int*   et    = (const int*)d_in[2];
    const int*   batch = (const int*)d_in[3];
    const float* W1    = (const float*)d_in[4];
    const float* root1 = (const float*)d_in[5];
    const float* b1    = (const float*)d_in[6];
    const float* W2    = (const float*)d_in[7];
    const float* root2 = (const float*)d_in[8];
    const float* b2    = (const float*)d_in[9];
    const float* lin_w = (const float*)d_in[10];
    const float* lin_b = (const float*)d_in[11];
    float* out = (float*)d_out;

    const int* src = ei;            // edge_index[0]
    const int* dst = ei + N_EDGES;  // edge_index[1]

    char* ws = (char*)d_ws;
    unsigned short* xb   = (unsigned short*)ws; ws += (size_t)N_NODES * HIDF * 2;  // 12.8 MB
    unsigned short* h1   = (unsigned short*)ws; ws += (size_t)N_NODES * HIDF * 2;  // 12.8 MB
    unsigned short* h2   = (unsigned short*)ws; ws += (size_t)N_NODES * HIDF * 2;  // 12.8 MB
    unsigned short* meanb= (unsigned short*)ws; ws += (size_t)N_NODES * KREL * 2;  // 102.4 MB
    unsigned short* wt1  = (unsigned short*)ws; ws += (size_t)HIDF * KTOT * 2;     // 288 KB
    unsigned short* wt2  = (unsigned short*)ws; ws += (size_t)HIDF * KTOT * 2;
    int*   cnt    = (int*)ws;   ws += (size_t)S_SEG * 4;
    int*   off    = (int*)ws;   ws += (size_t)S_SEG * 4;
    int*   bsum   = (int*)ws;   ws += 512 * 4;
    int*   cursor = (int*)ws;   ws += (size_t)S_SEG * 4;
    int*   sorted_src = (int*)ws; ws += (size_t)N_EDGES * 4;
    float* partial = (float*)ws; ws += (size_t)G_GRAPHS * PCHUNK * 128 * 4;        // 512 KB
    float* gmean  = (float*)ws; ws += (size_t)G_GRAPHS * HIDF * 4;

    hipMemsetAsync(cnt, 0, (size_t)S_SEG * 4, stream);

    // ---- counting sort of edges by (dst, rel) segment (XCD-partitioned) ----
    count_kernel<<<SORT_GRID, 256, 0, stream>>>(dst, et, cnt);
    scan1_kernel<<<NB_SCAN, SCAN_BLK, 0, stream>>>(cnt, off, bsum);
    scan2_kernel<<<1, 512, 0, stream>>>(bsum);
    absoff_kernel<<<(S_SEG + 255) / 256, 256, 0, stream>>>(off, bsum);
    hipMemcpyAsync(cursor, off, (size_t)S_SEG * 4, hipMemcpyDeviceToDevice, stream);
    bin_kernel<<<SORT_GRID, 256, 0, stream>>>(src, dst, et, cursor, sorted_src);

    // ---- bf16 conversions ----
    convx_kernel<<<(N_NODES * D_INF + 255) / 256, 256, 0, stream>>>(x, xb);
    convw_kernel<<<dim3(KTOT / 16, HIDF / 16), 256, 0, stream>>>(W1, root1, wt1);
    convw_kernel<<<dim3(KTOT / 16, HIDF / 16), 256, 0, stream>>>(W2, root2, wt2);

    // ---- layer 1 ----
    agg_kernel<<<S_SEG / 4, 256, 0, stream>>>(xb, sorted_src, off, cnt, meanb);
    gemm_mfma<<<(N_NODES + 127) / 128, 256, 0, stream>>>(meanb, xb, wt1, b1, h1);

    // ---- layer 2 ----
    agg_kernel<<<S_SEG / 4, 256, 0, stream>>>(h1, sorted_src, off, cnt, meanb);
    gemm_mfma<<<(N_NODES + 127) / 128, 256, 0, stream>>>(meanb, h1, wt2, b2, h2);

    // ---- pool (two-stage, no atomics) + classify ----
    pool1_kernel<<<dim3(G_GRAPHS, PCHUNK), 256, 0, stream>>>(h2, batch, partial);
    pool2_kernel<<<G_GRAPHS, 128, 0, stream>>>(partial, batch, gmean);
    final_kernel<<<G_GRAPHS, HIDF, 0, stream>>>(gmean, lin_w, lin_b, out);

    (void)in_sizes; (void)n_in; (void)out_size; (void)ws_size;
}

// Round 14
// 517.695 us; speedup vs baseline: 1.1707x; 1.1707x over previous
//
#include <hip/hip_runtime.h>

#define N_NODES 50000
#define N_EDGES 1600000
#define R_REL 8
#define G_GRAPHS 64
#define D_INF 128
#define HIDF 128
#define CLSF 10

#define S_SEG (N_NODES * R_REL)   // 400000 (dst, rel) segments
#define RZ 9                      // 8 relations + root slice
#define PCHUNK 16                 // pool stage-1 chunks per graph

#define XG 8                      // XCD groups for partitioned sort
#define NODES_PER_G (N_NODES / XG)      // 6250
#define SORT_BLKS_PER_G 256
#define SORT_GRID (XG * SORT_BLKS_PER_G)

typedef __attribute__((ext_vector_type(8))) short short8;
typedef __attribute__((ext_vector_type(4))) float floatx4;

typedef __attribute__((address_space(1))) const unsigned int guint;
typedef __attribute__((address_space(3))) unsigned int luint;
__device__ __forceinline__ void gload_lds16(const void* g, void* l) {
    // async global->LDS, 16 B/lane; LDS dest = wave-uniform base + lane*16
    __builtin_amdgcn_global_load_lds((guint*)g, (luint*)l, 16, 0, 0);
}

__device__ __forceinline__ unsigned short f2bf(float f) {
    unsigned int u = __float_as_uint(f);
    unsigned int r = (u + 0x7fffu + ((u >> 16) & 1u)) >> 16;   // RNE
    return (unsigned short)r;
}
// exact unpack of a packed bf16 pair (uint32) into two fp32
__device__ __forceinline__ float bflo(unsigned int u) { return __uint_as_float(u << 16); }
__device__ __forceinline__ float bfhi(unsigned int u) { return __uint_as_float(u & 0xffff0000u); }

// ---------------- count edges per (dst, rel) segment — XCD-partitioned --------
__global__ __launch_bounds__(256) void count_kernel(const int* __restrict__ dst,
                                                    const int* __restrict__ et,
                                                    int* __restrict__ cnt) {
    int xg = blockIdx.x & (XG - 1);
    int inner = blockIdx.x >> 3;
    int lo = xg * NODES_PER_G, hi = lo + NODES_PER_G;
    for (int e = inner * 256 + threadIdx.x; e < N_EDGES; e += SORT_BLKS_PER_G * 256) {
        int d = dst[e];
        if (d >= lo && d < hi) {
            atomicAdd(&cnt[d * R_REL + et[e]], 1);
        }
    }
}

// ---------------- two-level exclusive scan over segment counts ----------------
#define SCAN_BLK 256
#define SCAN_ELEMS 1024
#define NB_SCAN ((S_SEG + SCAN_ELEMS - 1) / SCAN_ELEMS)   // 391

__global__ __launch_bounds__(SCAN_BLK) void scan1_kernel(const int* __restrict__ cnt,
                                                         int* __restrict__ off,
                                                         int* __restrict__ bsum) {
    __shared__ int sd[SCAN_BLK];
    int t = threadIdx.x;
    int base = blockIdx.x * SCAN_ELEMS + t * 4;
    int v[4];
    int tsum = 0;
#pragma unroll
    for (int j = 0; j < 4; j++) {
        v[j] = (base + j < S_SEG) ? cnt[base + j] : 0;
        tsum += v[j];
    }
    sd[t] = tsum;
    __syncthreads();
    for (int d = 1; d < SCAN_BLK; d <<= 1) {
        int x = (t >= d) ? sd[t - d] : 0;
        __syncthreads();
        sd[t] += x;
        __syncthreads();
    }
    int incl = sd[t];
    int run = incl - tsum;
#pragma unroll
    for (int j = 0; j < 4; j++) {
        if (base + j < S_SEG) off[base + j] = run;
        run += v[j];
    }
    if (t == SCAN_BLK - 1) bsum[blockIdx.x] = incl;
}

__global__ __launch_bounds__(512) void scan2_kernel(int* __restrict__ bsum) {
    __shared__ int sd[512];
    int t = threadIdx.x;
    int v = (t < NB_SCAN) ? bsum[t] : 0;
    sd[t] = v;
    __syncthreads();
    for (int d = 1; d < 512; d <<= 1) {
        int x = (t >= d) ? sd[t - d] : 0;
        __syncthreads();
        sd[t] += x;
        __syncthreads();
    }
    if (t < NB_SCAN) bsum[t] = sd[t] - v;
}

// make off[] absolute (add block prefix)
__global__ void absoff_kernel(int* __restrict__ off, const int* __restrict__ bsum) {
    int i = blockIdx.x * blockDim.x + threadIdx.x;
    if (i < S_SEG) off[i] += bsum[i >> 10];
}

// ---------------- bin edges — XCD-partitioned; emit zidx + per-edge weight -----
// zidx[pos] = (src*9 + rel)*128 (element offset of the z row to gather)
// wgt[pos]  = 1/cnt[seg]  (mean weight; cnt>=1 since this edge exists)
__global__ __launch_bounds__(256) void bin_kernel(const int* __restrict__ src,
                                                  const int* __restrict__ dst,
                                                  const int* __restrict__ et,
                                                  const int* __restrict__ cnt,
                                                  int* __restrict__ cursor,
                                                  int* __restrict__ zidx,
                                                  float* __restrict__ wgt) {
    int xg = blockIdx.x & (XG - 1);
    int inner = blockIdx.x >> 3;
    int lo = xg * NODES_PER_G, hi = lo + NODES_PER_G;
    for (int e = inner * 256 + threadIdx.x; e < N_EDGES; e += SORT_BLKS_PER_G * 256) {
        int d = dst[e];
        if (d >= lo && d < hi) {
            int t = et[e];
            int seg = d * R_REL + t;
            int pos = atomicAdd(&cursor[seg], 1);    // absolute position
            zidx[pos] = (src[e] * RZ + t) << 7;      // *128
            wgt[pos] = 1.0f / (float)cnt[seg];
        }
    }
}

// ---------------- convert x fp32 -> bf16 compact [N,128] ----------------
__global__ void convx_kernel(const float* __restrict__ x, unsigned short* __restrict__ xb) {
    int idx = blockIdx.x * blockDim.x + threadIdx.x;
    if (idx < N_NODES * D_INF) xb[idx] = f2bf(x[idx]);
}

// ---------------- build bf16 weights wz[9][128][128]: [r][col][k] ----------
// r<8: wz[r][c][k] = W[r][k][c]; r==8: wz[8][c][k] = root[k][c]
__global__ __launch_bounds__(256) void convw9_kernel(const float* __restrict__ W,
                                                     const float* __restrict__ root,
                                                     unsigned short* __restrict__ wz) {
    __shared__ float t[16][17];
    int r = blockIdx.z;
    int k0 = blockIdx.x * 16, c0 = blockIdx.y * 16;
    int tx = threadIdx.x & 15, ty = threadIdx.x >> 4;
    const float* srcp = (r < 8) ? (W + (size_t)r * 128 * 128) : root;
    t[ty][tx] = srcp[(size_t)(k0 + ty) * 128 + c0 + tx];
    __syncthreads();
    wz[(size_t)r * 16384 + (size_t)(c0 + ty) * 128 + k0 + tx] = f2bf(t[tx][ty]);
}

// ---------------- transform GEMM: z[n][r][c] = sum_k h[n][k] * wz[r][c][k] -----
// M=128 tile; A (h rows, 32 KB as 4 k-chunks) staged ONCE and reused across all
// 9 relation slices; B slice chunks (8 KB) streamed from L2. No giant K-stream.
__global__ __launch_bounds__(256) void transform_gemm(
    const unsigned short* __restrict__ hb,   // [N,128] bf16
    const unsigned short* __restrict__ wz,   // [9][128][128] bf16 [r][col][k]
    unsigned short* __restrict__ z)          // [N][9][128] bf16
{
    __shared__ __align__(16) unsigned short A4[4][128][32];  // 32 KB
    __shared__ __align__(16) unsigned short Bc[128][32];     // 8 KB

    const int tx = threadIdx.x;
    const int wave = tx >> 6, lane = tx & 63;
    const int quad = lane >> 4, lq = lane & 15;
    const int row0 = blockIdx.x * 128;
    const int srow = lane >> 2;    // 0..15
    const int sch  = lane & 3;     // 16-B chunk

    // ---- stage all of A once: 4 k-chunks x (2 calls/wave) ----
#pragma unroll
    for (int kk = 0; kk < 4; kk++) {
#pragma unroll
        for (int p = 0; p < 2; p++) {
            int rr = (wave * 2 + p) * 16;
            int gr = row0 + rr + srow; if (gr >= N_NODES) gr = N_NODES - 1;
            gload_lds16(hb + (size_t)gr * HIDF + kk * 32 + sch * 8, &A4[kk][rr][0]);
        }
    }

    floatx4 acc[2][8];
    for (int r = 0; r < RZ; r++) {
#pragma unroll
        for (int i = 0; i < 2; i++)
#pragma unroll
            for (int j = 0; j < 8; j++) acc[i][j] = (floatx4){0.f, 0.f, 0.f, 0.f};

#pragma unroll
        for (int kk = 0; kk < 4; kk++) {
            // stage B chunk: cols (wave*2+p)*16 + srow, k-range kk*32
#pragma unroll
            for (int p = 0; p < 2; p++) {
                int cc = (wave * 2 + p) * 16;
                int gc = cc + srow;
                gload_lds16(wz + ((size_t)r * 128 + gc) * 128 + kk * 32 + sch * 8,
                            &Bc[cc][0]);
            }
            __syncthreads();

            short8 af[2], bfr[8];
#pragma unroll
            for (int i = 0; i < 2; i++)
                af[i] = *(const short8*)(&A4[kk][wave * 32 + i * 16 + lq][quad * 8]);
#pragma unroll
            for (int j = 0; j < 8; j++)
                bfr[j] = *(const short8*)(&Bc[j * 16 + lq][quad * 8]);
#pragma unroll
            for (int i = 0; i < 2; i++)
#pragma unroll
                for (int j = 0; j < 8; j++)
                    acc[i][j] = __builtin_amdgcn_mfma_f32_16x16x32_bf16(af[i], bfr[j], acc[i][j], 0, 0, 0);
            __syncthreads();
        }

        // write z slice r (C/D layout col=lane&15, row=quad*4+reg)
#pragma unroll
        for (int i = 0; i < 2; i++) {
#pragma unroll
            for (int j = 0; j < 8; j++) {
                int col = j * 16 + lq;
#pragma unroll
                for (int rg = 0; rg < 4; rg++) {
                    int row = row0 + wave * 32 + i * 16 + quad * 4 + rg;
                    if (row < N_NODES)
                        z[((size_t)row * RZ + r) * 128 + col] = f2bf(acc[i][j][rg]);
                }
            }
        }
    }
}

// ---------------- aggregate: flat weighted gather per node + root + bias + relu
// Half-wave (32 lanes) per node — round-12's proven gather shape (4-unrolled
// independent uint2 row-gathers). Edges of a node are CONTIGUOUS in sorted order.
__global__ __launch_bounds__(256) void agg2_kernel(const unsigned short* __restrict__ z,
                                                   const int* __restrict__ zidx,
                                                   const float* __restrict__ wgt,
                                                   const int* __restrict__ off,  // absolute
                                                   const float* __restrict__ bias,
                                                   unsigned short* __restrict__ hout) {
    int nod = blockIdx.x * 8 + (threadIdx.x >> 5);
    if (nod >= N_NODES) return;
    int c = threadIdx.x & 31;          // lane covers 4 channels (uint2)
    int beg = off[nod * R_REL];
    int end = (nod < N_NODES - 1) ? off[(nod + 1) * R_REL] : N_EDGES;

    float a0 = 0.f, a1 = 0.f, a2 = 0.f, a3 = 0.f;
    int e = beg;
    for (; e + 4 <= end; e += 4) {
        int z0 = zidx[e + 0], z1 = zidx[e + 1], z2 = zidx[e + 2], z3 = zidx[e + 3];
        float w0 = wgt[e + 0], w1 = wgt[e + 1], w2 = wgt[e + 2], w3 = wgt[e + 3];
        uint2 v0 = *(const uint2*)(z + (size_t)z0 + c * 4);
        uint2 v1 = *(const uint2*)(z + (size_t)z1 + c * 4);
        uint2 v2 = *(const uint2*)(z + (size_t)z2 + c * 4);
        uint2 v3 = *(const uint2*)(z + (size_t)z3 + c * 4);
        a0 += bflo(v0.x) * w0 + bflo(v1.x) * w1 + bflo(v2.x) * w2 + bflo(v3.x) * w3;
        a1 += bfhi(v0.x) * w0 + bfhi(v1.x) * w1 + bfhi(v2.x) * w2 + bfhi(v3.x) * w3;
        a2 += bflo(v0.y) * w0 + bflo(v1.y) * w1 + bflo(v2.y) * w2 + bflo(v3.y) * w3;
        a3 += bfhi(v0.y) * w0 + bfhi(v1.y) * w1 + bfhi(v2.y) * w2 + bfhi(v3.y) * w3;
    }
    for (; e < end; e++) {
        int zi = zidx[e];
        float w = wgt[e];
        uint2 v = *(const uint2*)(z + (size_t)zi + c * 4);
        a0 += bflo(v.x) * w; a1 += bfhi(v.x) * w;
        a2 += bflo(v.y) * w; a3 += bfhi(v.y) * w;
    }
    // root slice (weight 1)
    uint2 vr = *(const uint2*)(z + ((size_t)nod * RZ + 8) * 128 + c * 4);
    a0 += bflo(vr.x); a1 += bfhi(vr.x); a2 += bflo(vr.y); a3 += bfhi(vr.y);
    float4 b = *(const float4*)(bias + c * 4);
    a0 = fmaxf(a0 + b.x, 0.0f);
    a1 = fmaxf(a1 + b.y, 0.0f);
    a2 = fmaxf(a2 + b.z, 0.0f);
    a3 = fmaxf(a3 + b.w, 0.0f);
    uint2 o;
    o.x = (unsigned int)f2bf(a0) | ((unsigned int)f2bf(a1) << 16);
    o.y = (unsigned int)f2bf(a2) | ((unsigned int)f2bf(a3) << 16);
    *(uint2*)(hout + (size_t)nod * HIDF + c * 4) = o;
}

// ---------------- global mean pool, two-stage, no atomics ----------------
__global__ __launch_bounds__(256) void pool1_kernel(const unsigned short* __restrict__ h,
                                                    const int* __restrict__ batch,
                                                    float* __restrict__ partial) {  // [G][PCHUNK][128]
    int g = blockIdx.x;
    int p = blockIdx.y;
    int lo, hi;
    {
        int l = 0, r = N_NODES;
        while (l < r) { int m = (l + r) >> 1; if (batch[m] < g) l = m + 1; else r = m; }
        lo = l;
        l = lo; r = N_NODES;
        while (l < r) { int m = (l + r) >> 1; if (batch[m] < g + 1) l = m + 1; else r = m; }
        hi = l;
    }
    int t = threadIdx.x;
    int rowlane = t >> 5;
    int c4 = t & 31;
    float a0 = 0.f, a1 = 0.f, a2 = 0.f, a3 = 0.f;
    for (int n = lo + p + rowlane * PCHUNK; n < hi; n += 8 * PCHUNK) {
        uint2 v = *(const uint2*)(h + (size_t)n * HIDF + c4 * 4);
        a0 += bflo(v.x); a1 += bfhi(v.x); a2 += bflo(v.y); a3 += bfhi(v.y);
    }
    __shared__ float red[8][128];
    if (rowlane == 0) {
        red[0][c4 * 4 + 0] = a0; red[0][c4 * 4 + 1] = a1;
        red[0][c4 * 4 + 2] = a2; red[0][c4 * 4 + 3] = a3;
    }
    __syncthreads();
    for (int s = 1; s < 8; s++) {
        if (rowlane == s) {
            red[0][c4 * 4 + 0] += a0; red[0][c4 * 4 + 1] += a1;
            red[0][c4 * 4 + 2] += a2; red[0][c4 * 4 + 3] += a3;
        }
        __syncthreads();
    }
    if (t < 128) partial[((size_t)g * PCHUNK + p) * 128 + t] = red[0][t];
}

__global__ __launch_bounds__(128) void pool2_kernel(const float* __restrict__ partial,
                                                    const int* __restrict__ batch,
                                                    float* __restrict__ gmean) {
    int g = blockIdx.x;
    int lo, hi;
    {
        int l = 0, r = N_NODES;
        while (l < r) { int m = (l + r) >> 1; if (batch[m] < g) l = m + 1; else r = m; }
        lo = l;
        l = lo; r = N_NODES;
        while (l < r) { int m = (l + r) >> 1; if (batch[m] < g + 1) l = m + 1; else r = m; }
        hi = l;
    }
    int t = threadIdx.x;
    float s = 0.f;
#pragma unroll
    for (int p = 0; p < PCHUNK; p++)
        s += partial[((size_t)g * PCHUNK + p) * 128 + t];
    gmean[g * HIDF + t] = s / (float)max(hi - lo, 1);
}

// ---------------- final linear ----------------
__global__ void final_kernel(const float* __restrict__ gmean,
                             const float* __restrict__ lin_w,  // [128, 10]
                             const float* __restrict__ lin_b,  // [10]
                             float* __restrict__ out) {        // [64, 10]
    __shared__ float gl[HIDF];
    int g = blockIdx.x;
    int hh = threadIdx.x;
    gl[hh] = gmean[g * HIDF + hh];
    __syncthreads();
    if (hh < CLSF) {
        float s = lin_b[hh];
#pragma unroll 16
        for (int d = 0; d < HIDF; d++) s += gl[d] * lin_w[d * CLSF + hh];
        out[g * CLSF + hh] = s;
    }
}

extern "C" void kernel_launch(void* const* d_in, const int* in_sizes, int n_in,
                              void* d_out, int out_size, void* d_ws, size_t ws_size,
                              hipStream_t stream) {
    const float* x     = (const float*)d_in[0];
    const int*   ei    = (const int*)d_in[1];
    const int*   et    = (const int*)d_in[2];
    const int*   batch = (const int*)d_in[3];
    const float* W1    = (const float*)d_in[4];
    const float* root1 = (const float*)d_in[5];
    const float* b1    = (const float*)d_in[6];
    const float* W2    = (const float*)d_in[7];
    const float* root2 = (const float*)d_in[8];
    const float* b2    = (const float*)d_in[9];
    const float* lin_w = (const float*)d_in[10];
    const float* lin_b = (const float*)d_in[11];
    float* out = (float*)d_out;

    const int* src = ei;            // edge_index[0]
    const int* dst = ei + N_EDGES;  // edge_index[1]

    char* ws = (char*)d_ws;
    unsigned short* xb  = (unsigned short*)ws; ws += (size_t)N_NODES * HIDF * 2;   // 12.8 MB
    unsigned short* h1  = (unsigned short*)ws; ws += (size_t)N_NODES * HIDF * 2;   // 12.8 MB
    unsigned short* h2  = (unsigned short*)ws; ws += (size_t)N_NODES * HIDF * 2;   // 12.8 MB
    unsigned short* z   = (unsigned short*)ws; ws += (size_t)N_NODES * RZ * 128 * 2; // 115.2 MB
    unsigned short* wz1 = (unsigned short*)ws; ws += (size_t)RZ * 128 * 128 * 2;   // 288 KB
    unsigned short* wz2 = (unsigned short*)ws; ws += (size_t)RZ * 128 * 128 * 2;
    int*   cnt    = (int*)ws;   ws += (size_t)S_SEG * 4;
    int*   off    = (int*)ws;   ws += (size_t)S_SEG * 4;
    int*   bsum   = (int*)ws;   ws += 512 * 4;
    int*   cursor = (int*)ws;   ws += (size_t)S_SEG * 4;
    int*   zidx   = (int*)ws;   ws += (size_t)N_EDGES * 4;                          // 6.4 MB
    float* wgt    = (float*)ws; ws += (size_t)N_EDGES * 4;                          // 6.4 MB
    float* partial = (float*)ws; ws += (size_t)G_GRAPHS * PCHUNK * 128 * 4;
    float* gmean  = (float*)ws; ws += (size_t)G_GRAPHS * HIDF * 4;

    hipMemsetAsync(cnt, 0, (size_t)S_SEG * 4, stream);

    // ---- counting sort of edges by (dst, rel) segment (XCD-partitioned) ----
    count_kernel<<<SORT_GRID, 256, 0, stream>>>(dst, et, cnt);
    scan1_kernel<<<NB_SCAN, SCAN_BLK, 0, stream>>>(cnt, off, bsum);
    scan2_kernel<<<1, 512, 0, stream>>>(bsum);
    absoff_kernel<<<(S_SEG + 255) / 256, 256, 0, stream>>>(off, bsum);
    hipMemcpyAsync(cursor, off, (size_t)S_SEG * 4, hipMemcpyDeviceToDevice, stream);
    bin_kernel<<<SORT_GRID, 256, 0, stream>>>(src, dst, et, cnt, cursor, zidx, wgt);

    // ---- bf16 conversions ----
    convx_kernel<<<(N_NODES * D_INF + 255) / 256, 256, 0, stream>>>(x, xb);
    convw9_kernel<<<dim3(8, 8, RZ), 256, 0, stream>>>(W1, root1, wz1);
    convw9_kernel<<<dim3(8, 8, RZ), 256, 0, stream>>>(W2, root2, wz2);

    const int NGB = (N_NODES + 127) / 128;   // 391
    const int NAB = (N_NODES + 7) / 8;       // 6250

    // ---- layer 1: transform then aggregate ----
    transform_gemm<<<NGB, 256, 0, stream>>>(xb, wz1, z);
    agg2_kernel<<<NAB, 256, 0, stream>>>(z, zidx, wgt, off, b1, h1);

    // ---- layer 2 ----
    transform_gemm<<<NGB, 256, 0, stream>>>(h1, wz2, z);
    agg2_kernel<<<NAB, 256, 0, stream>>>(z, zidx, wgt, off, b2, h2);

    // ---- pool (two-stage, no atomics) + classify ----
    pool1_kernel<<<dim3(G_GRAPHS, PCHUNK), 256, 0, stream>>>(h2, batch, partial);
    pool2_kernel<<<G_GRAPHS, 128, 0, stream>>>(partial, batch, gmean);
    final_kernel<<<G_GRAPHS, HIDF, 0, stream>>>(gmean, lin_w, lin_b, out);

    (void)in_sizes; (void)n_in; (void)out_size; (void)ws_size;
}

// Round 15
// 488.739 us; speedup vs baseline: 1.2400x; 1.0592x over previous
//
#include <hip/hip_runtime.h>

#define N_NODES 50000
#define N_EDGES 1600000
#define R_REL 8
#define G_GRAPHS 64
#define D_INF 128
#define HIDF 128
#define CLSF 10

#define S_SEG (N_NODES * R_REL)   // 400000 (dst, rel) segments
#define RZ 9                      // 8 relations + root slice
#define PCHUNK 16                 // pool stage-1 chunks per graph

#define XG 8                      // XCD groups for partitioned sort
#define NODES_PER_G (N_NODES / XG)      // 6250
#define SORT_BLKS_PER_G 256
#define SORT_GRID (XG * SORT_BLKS_PER_G)

typedef __attribute__((ext_vector_type(8))) short short8;
typedef __attribute__((ext_vector_type(4))) float floatx4;

typedef __attribute__((address_space(1))) const unsigned int guint;
typedef __attribute__((address_space(3))) unsigned int luint;
__device__ __forceinline__ void gload_lds16(const void* g, void* l) {
    // async global->LDS, 16 B/lane; LDS dest = wave-uniform base + lane*16
    __builtin_amdgcn_global_load_lds((guint*)g, (luint*)l, 16, 0, 0);
}

__device__ __forceinline__ unsigned short f2bf(float f) {
    unsigned int u = __float_as_uint(f);
    unsigned int r = (u + 0x7fffu + ((u >> 16) & 1u)) >> 16;   // RNE
    return (unsigned short)r;
}
// exact unpack of a packed bf16 pair (uint32) into two fp32
__device__ __forceinline__ float bflo(unsigned int u) { return __uint_as_float(u << 16); }
__device__ __forceinline__ float bfhi(unsigned int u) { return __uint_as_float(u & 0xffff0000u); }

// ---------------- count edges per (dst, rel) segment — XCD-partitioned --------
__global__ __launch_bounds__(256) void count_kernel(const int* __restrict__ dst,
                                                    const int* __restrict__ et,
                                                    int* __restrict__ cnt) {
    int xg = blockIdx.x & (XG - 1);
    int inner = blockIdx.x >> 3;
    int lo = xg * NODES_PER_G, hi = lo + NODES_PER_G;
    for (int e = inner * 256 + threadIdx.x; e < N_EDGES; e += SORT_BLKS_PER_G * 256) {
        int d = dst[e];
        if (d >= lo && d < hi) {
            atomicAdd(&cnt[d * R_REL + et[e]], 1);
        }
    }
}

// ---------------- two-level exclusive scan over segment counts ----------------
#define SCAN_BLK 256
#define SCAN_ELEMS 1024
#define NB_SCAN ((S_SEG + SCAN_ELEMS - 1) / SCAN_ELEMS)   // 391

__global__ __launch_bounds__(SCAN_BLK) void scan1_kernel(const int* __restrict__ cnt,
                                                         int* __restrict__ off,
                                                         int* __restrict__ bsum) {
    __shared__ int sd[SCAN_BLK];
    int t = threadIdx.x;
    int base = blockIdx.x * SCAN_ELEMS + t * 4;
    int v[4];
    int tsum = 0;
#pragma unroll
    for (int j = 0; j < 4; j++) {
        v[j] = (base + j < S_SEG) ? cnt[base + j] : 0;
        tsum += v[j];
    }
    sd[t] = tsum;
    __syncthreads();
    for (int d = 1; d < SCAN_BLK; d <<= 1) {
        int x = (t >= d) ? sd[t - d] : 0;
        __syncthreads();
        sd[t] += x;
        __syncthreads();
    }
    int incl = sd[t];
    int run = incl - tsum;
#pragma unroll
    for (int j = 0; j < 4; j++) {
        if (base + j < S_SEG) off[base + j] = run;
        run += v[j];
    }
    if (t == SCAN_BLK - 1) bsum[blockIdx.x] = incl;
}

__global__ __launch_bounds__(512) void scan2_kernel(int* __restrict__ bsum) {
    __shared__ int sd[512];
    int t = threadIdx.x;
    int v = (t < NB_SCAN) ? bsum[t] : 0;
    sd[t] = v;
    __syncthreads();
    for (int d = 1; d < 512; d <<= 1) {
        int x = (t >= d) ? sd[t - d] : 0;
        __syncthreads();
        sd[t] += x;
        __syncthreads();
    }
    if (t < NB_SCAN) bsum[t] = sd[t] - v;
}

// make off[] absolute (add block prefix) + precompute winv = 1/cnt
__global__ void absoff_kernel(int* __restrict__ off, const int* __restrict__ bsum,
                              const int* __restrict__ cnt, float* __restrict__ winv) {
    int i = blockIdx.x * blockDim.x + threadIdx.x;
    if (i < S_SEG) {
        off[i] += bsum[i >> 10];
        winv[i] = 1.0f / (float)max(cnt[i], 1);
    }
}

// ---------------- bin edges — XCD-partitioned; single packed 8B record --------
// zw[pos] = { (src*9+rel)*128 , bits(1/cnt[seg]) } — ONE int2 store per edge.
__global__ __launch_bounds__(256) void bin_kernel(const int* __restrict__ src,
                                                  const int* __restrict__ dst,
                                                  const int* __restrict__ et,
                                                  const float* __restrict__ winv,
                                                  int* __restrict__ cursor,
                                                  int2* __restrict__ zw) {
    int xg = blockIdx.x & (XG - 1);
    int inner = blockIdx.x >> 3;
    int lo = xg * NODES_PER_G, hi = lo + NODES_PER_G;
    for (int e = inner * 256 + threadIdx.x; e < N_EDGES; e += SORT_BLKS_PER_G * 256) {
        int d = dst[e];
        if (d >= lo && d < hi) {
            int t = et[e];
            int seg = d * R_REL + t;
            int pos = atomicAdd(&cursor[seg], 1);    // absolute position
            zw[pos] = make_int2((src[e] * RZ + t) << 7, __float_as_int(winv[seg]));
        }
    }
}

// ---------------- convert x fp32 -> bf16 compact [N,128] ----------------
__global__ void convx_kernel(const float* __restrict__ x, unsigned short* __restrict__ xb) {
    int idx = blockIdx.x * blockDim.x + threadIdx.x;
    if (idx < N_NODES * D_INF) xb[idx] = f2bf(x[idx]);
}

// ---------------- build bf16 weights wz[9][128][128]: [r][col][k] ----------
__global__ __launch_bounds__(256) void convw9_kernel(const float* __restrict__ W,
                                                     const float* __restrict__ root,
                                                     unsigned short* __restrict__ wz) {
    __shared__ float t[16][17];
    int r = blockIdx.z;
    int k0 = blockIdx.x * 16, c0 = blockIdx.y * 16;
    int tx = threadIdx.x & 15, ty = threadIdx.x >> 4;
    const float* srcp = (r < 8) ? (W + (size_t)r * 128 * 128) : root;
    t[ty][tx] = srcp[(size_t)(k0 + ty) * 128 + c0 + tx];
    __syncthreads();
    wz[(size_t)r * 16384 + (size_t)(c0 + ty) * 128 + k0 + tx] = f2bf(t[tx][ty]);
}

// ---------------- transform GEMM: z[n][r][c] = sum_k h[n][k] * wz[r][c][k] -----
__global__ __launch_bounds__(256) void transform_gemm(
    const unsigned short* __restrict__ hb,   // [N,128] bf16
    const unsigned short* __restrict__ wz,   // [9][128][128] bf16 [r][col][k]
    unsigned short* __restrict__ z)          // [N][9][128] bf16
{
    __shared__ __align__(16) unsigned short A4[4][128][32];  // 32 KB
    __shared__ __align__(16) unsigned short Bc[128][32];     // 8 KB

    const int tx = threadIdx.x;
    const int wave = tx >> 6, lane = tx & 63;
    const int quad = lane >> 4, lq = lane & 15;
    const int row0 = blockIdx.x * 128;
    const int srow = lane >> 2;    // 0..15
    const int sch  = lane & 3;     // 16-B chunk

    // ---- stage all of A once: 4 k-chunks x (2 calls/wave) ----
#pragma unroll
    for (int kk = 0; kk < 4; kk++) {
#pragma unroll
        for (int p = 0; p < 2; p++) {
            int rr = (wave * 2 + p) * 16;
            int gr = row0 + rr + srow; if (gr >= N_NODES) gr = N_NODES - 1;
            gload_lds16(hb + (size_t)gr * HIDF + kk * 32 + sch * 8, &A4[kk][rr][0]);
        }
    }

    floatx4 acc[2][8];
    for (int r = 0; r < RZ; r++) {
#pragma unroll
        for (int i = 0; i < 2; i++)
#pragma unroll
            for (int j = 0; j < 8; j++) acc[i][j] = (floatx4){0.f, 0.f, 0.f, 0.f};

#pragma unroll
        for (int kk = 0; kk < 4; kk++) {
#pragma unroll
            for (int p = 0; p < 2; p++) {
                int cc = (wave * 2 + p) * 16;
                int gc = cc + srow;
                gload_lds16(wz + ((size_t)r * 128 + gc) * 128 + kk * 32 + sch * 8,
                            &Bc[cc][0]);
            }
            __syncthreads();

            short8 af[2], bfr[8];
#pragma unroll
            for (int i = 0; i < 2; i++)
                af[i] = *(const short8*)(&A4[kk][wave * 32 + i * 16 + lq][quad * 8]);
#pragma unroll
            for (int j = 0; j < 8; j++)
                bfr[j] = *(const short8*)(&Bc[j * 16 + lq][quad * 8]);
#pragma unroll
            for (int i = 0; i < 2; i++)
#pragma unroll
                for (int j = 0; j < 8; j++)
                    acc[i][j] = __builtin_amdgcn_mfma_f32_16x16x32_bf16(af[i], bfr[j], acc[i][j], 0, 0, 0);
            __syncthreads();
        }

        // write z slice r (C/D layout col=lane&15, row=quad*4+reg)
#pragma unroll
        for (int i = 0; i < 2; i++) {
#pragma unroll
            for (int j = 0; j < 8; j++) {
                int col = j * 16 + lq;
#pragma unroll
                for (int rg = 0; rg < 4; rg++) {
                    int row = row0 + wave * 32 + i * 16 + quad * 4 + rg;
                    if (row < N_NODES)
                        z[((size_t)row * RZ + r) * 128 + col] = f2bf(acc[i][j][rg]);
                }
            }
        }
    }
}

// ---------------- aggregate: flat weighted gather per node + root + bias + relu
__global__ __launch_bounds__(256) void agg2_kernel(const unsigned short* __restrict__ z,
                                                   const int2* __restrict__ zw,
                                                   const int* __restrict__ off,  // absolute
                                                   const float* __restrict__ bias,
                                                   unsigned short* __restrict__ hout) {
    int nod = blockIdx.x * 8 + (threadIdx.x >> 5);
    if (nod >= N_NODES) return;
    int c = threadIdx.x & 31;          // lane covers 4 channels (uint2)
    int beg = off[nod * R_REL];
    int end = (nod < N_NODES - 1) ? off[(nod + 1) * R_REL] : N_EDGES;

    float a0 = 0.f, a1 = 0.f, a2 = 0.f, a3 = 0.f;
    int e = beg;
    for (; e + 4 <= end; e += 4) {
        int2 r0 = zw[e + 0], r1 = zw[e + 1], r2 = zw[e + 2], r3 = zw[e + 3];
        float w0 = __int_as_float(r0.y), w1 = __int_as_float(r1.y);
        float w2 = __int_as_float(r2.y), w3 = __int_as_float(r3.y);
        uint2 v0 = *(const uint2*)(z + (size_t)r0.x + c * 4);
        uint2 v1 = *(const uint2*)(z + (size_t)r1.x + c * 4);
        uint2 v2 = *(const uint2*)(z + (size_t)r2.x + c * 4);
        uint2 v3 = *(const uint2*)(z + (size_t)r3.x + c * 4);
        a0 += bflo(v0.x) * w0 + bflo(v1.x) * w1 + bflo(v2.x) * w2 + bflo(v3.x) * w3;
        a1 += bfhi(v0.x) * w0 + bfhi(v1.x) * w1 + bfhi(v2.x) * w2 + bfhi(v3.x) * w3;
        a2 += bflo(v0.y) * w0 + bflo(v1.y) * w1 + bflo(v2.y) * w2 + bflo(v3.y) * w3;
        a3 += bfhi(v0.y) * w0 + bfhi(v1.y) * w1 + bfhi(v2.y) * w2 + bfhi(v3.y) * w3;
    }
    for (; e < end; e++) {
        int2 rr = zw[e];
        float w = __int_as_float(rr.y);
        uint2 v = *(const uint2*)(z + (size_t)rr.x + c * 4);
        a0 += bflo(v.x) * w; a1 += bfhi(v.x) * w;
        a2 += bflo(v.y) * w; a3 += bfhi(v.y) * w;
    }
    // root slice (weight 1)
    uint2 vr = *(const uint2*)(z + ((size_t)nod * RZ + 8) * 128 + c * 4);
    a0 += bflo(vr.x); a1 += bfhi(vr.x); a2 += bflo(vr.y); a3 += bfhi(vr.y);
    float4 b = *(const float4*)(bias + c * 4);
    a0 = fmaxf(a0 + b.x, 0.0f);
    a1 = fmaxf(a1 + b.y, 0.0f);
    a2 = fmaxf(a2 + b.z, 0.0f);
    a3 = fmaxf(a3 + b.w, 0.0f);
    uint2 o;
    o.x = (unsigned int)f2bf(a0) | ((unsigned int)f2bf(a1) << 16);
    o.y = (unsigned int)f2bf(a2) | ((unsigned int)f2bf(a3) << 16);
    *(uint2*)(hout + (size_t)nod * HIDF + c * 4) = o;
}

// ---------------- global mean pool, two-stage, no atomics ----------------
__global__ __launch_bounds__(256) void pool1_kernel(const unsigned short* __restrict__ h,
                                                    const int* __restrict__ batch,
                                                    float* __restrict__ partial) {  // [G][PCHUNK][128]
    int g = blockIdx.x;
    int p = blockIdx.y;
    int lo, hi;
    {
        int l = 0, r = N_NODES;
        while (l < r) { int m = (l + r) >> 1; if (batch[m] < g) l = m + 1; else r = m; }
        lo = l;
        l = lo; r = N_NODES;
        while (l < r) { int m = (l + r) >> 1; if (batch[m] < g + 1) l = m + 1; else r = m; }
        hi = l;
    }
    int t = threadIdx.x;
    int rowlane = t >> 5;
    int c4 = t & 31;
    float a0 = 0.f, a1 = 0.f, a2 = 0.f, a3 = 0.f;
    for (int n = lo + p + rowlane * PCHUNK; n < hi; n += 8 * PCHUNK) {
        uint2 v = *(const uint2*)(h + (size_t)n * HIDF + c4 * 4);
        a0 += bflo(v.x); a1 += bfhi(v.x); a2 += bflo(v.y); a3 += bfhi(v.y);
    }
    __shared__ float red[8][128];
    if (rowlane == 0) {
        red[0][c4 * 4 + 0] = a0; red[0][c4 * 4 + 1] = a1;
        red[0][c4 * 4 + 2] = a2; red[0][c4 * 4 + 3] = a3;
    }
    __syncthreads();
    for (int s = 1; s < 8; s++) {
        if (rowlane == s) {
            red[0][c4 * 4 + 0] += a0; red[0][c4 * 4 + 1] += a1;
            red[0][c4 * 4 + 2] += a2; red[0][c4 * 4 + 3] += a3;
        }
        __syncthreads();
    }
    if (t < 128) partial[((size_t)g * PCHUNK + p) * 128 + t] = red[0][t];
}

__global__ __launch_bounds__(128) void pool2_kernel(const float* __restrict__ partial,
                                                    const int* __restrict__ batch,
                                                    float* __restrict__ gmean) {
    int g = blockIdx.x;
    int lo, hi;
    {
        int l = 0, r = N_NODES;
        while (l < r) { int m = (l + r) >> 1; if (batch[m] < g) l = m + 1; else r = m; }
        lo = l;
        l = lo; r = N_NODES;
        while (l < r) { int m = (l + r) >> 1; if (batch[m] < g + 1) l = m + 1; else r = m; }
        hi = l;
    }
    int t = threadIdx.x;
    float s = 0.f;
#pragma unroll
    for (int p = 0; p < PCHUNK; p++)
        s += partial[((size_t)g * PCHUNK + p) * 128 + t];
    gmean[g * HIDF + t] = s / (float)max(hi - lo, 1);
}

// ---------------- final linear ----------------
__global__ void final_kernel(const float* __restrict__ gmean,
                             const float* __restrict__ lin_w,  // [128, 10]
                             const float* __restrict__ lin_b,  // [10]
                             float* __restrict__ out) {        // [64, 10]
    __shared__ float gl[HIDF];
    int g = blockIdx.x;
    int hh = threadIdx.x;
    gl[hh] = gmean[g * HIDF + hh];
    __syncthreads();
    if (hh < CLSF) {
        float s = lin_b[hh];
#pragma unroll 16
        for (int d = 0; d < HIDF; d++) s += gl[d] * lin_w[d * CLSF + hh];
        out[g * CLSF + hh] = s;
    }
}

extern "C" void kernel_launch(void* const* d_in, const int* in_sizes, int n_in,
                              void* d_out, int out_size, void* d_ws, size_t ws_size,
                              hipStream_t stream) {
    const float* x     = (const float*)d_in[0];
    const int*   ei    = (const int*)d_in[1];
    const int*   et    = (const int*)d_in[2];
    const int*   batch = (const int*)d_in[3];
    const float* W1    = (const float*)d_in[4];
    const float* root1 = (const float*)d_in[5];
    const float* b1    = (const float*)d_in[6];
    const float* W2    = (const float*)d_in[7];
    const float* root2 = (const float*)d_in[8];
    const float* b2    = (const float*)d_in[9];
    const float* lin_w = (const float*)d_in[10];
    const float* lin_b = (const float*)d_in[11];
    float* out = (float*)d_out;

    const int* src = ei;            // edge_index[0]
    const int* dst = ei + N_EDGES;  // edge_index[1]

    char* ws = (char*)d_ws;
    unsigned short* xb  = (unsigned short*)ws; ws += (size_t)N_NODES * HIDF * 2;   // 12.8 MB
    unsigned short* h1  = (unsigned short*)ws; ws += (size_t)N_NODES * HIDF * 2;   // 12.8 MB
    unsigned short* h2  = (unsigned short*)ws; ws += (size_t)N_NODES * HIDF * 2;   // 12.8 MB
    unsigned short* z   = (unsigned short*)ws; ws += (size_t)N_NODES * RZ * 128 * 2; // 115.2 MB
    unsigned short* wz1 = (unsigned short*)ws; ws += (size_t)RZ * 128 * 128 * 2;   // 288 KB
    unsigned short* wz2 = (unsigned short*)ws; ws += (size_t)RZ * 128 * 128 * 2;
    int*   cnt    = (int*)ws;   ws += (size_t)S_SEG * 4;
    int*   off    = (int*)ws;   ws += (size_t)S_SEG * 4;
    int*   bsum   = (int*)ws;   ws += 512 * 4;
    int*   cursor = (int*)ws;   ws += (size_t)S_SEG * 4;
    float* winv   = (float*)ws; ws += (size_t)S_SEG * 4;                            // 1.6 MB
    int2*  zw     = (int2*)ws;  ws += (size_t)N_EDGES * 8;                          // 12.8 MB
    float* partial = (float*)ws; ws += (size_t)G_GRAPHS * PCHUNK * 128 * 4;
    float* gmean  = (float*)ws; ws += (size_t)G_GRAPHS * HIDF * 4;

    hipMemsetAsync(cnt, 0, (size_t)S_SEG * 4, stream);

    // ---- counting sort of edges by (dst, rel) segment (XCD-partitioned) ----
    count_kernel<<<SORT_GRID, 256, 0, stream>>>(dst, et, cnt);
    scan1_kernel<<<NB_SCAN, SCAN_BLK, 0, stream>>>(cnt, off, bsum);
    scan2_kernel<<<1, 512, 0, stream>>>(bsum);
    absoff_kernel<<<(S_SEG + 255) / 256, 256, 0, stream>>>(off, bsum, cnt, winv);
    hipMemcpyAsync(cursor, off, (size_t)S_SEG * 4, hipMemcpyDeviceToDevice, stream);
    bin_kernel<<<SORT_GRID, 256, 0, stream>>>(src, dst, et, winv, cursor, zw);

    // ---- bf16 conversions ----
    convx_kernel<<<(N_NODES * D_INF + 255) / 256, 256, 0, stream>>>(x, xb);
    convw9_kernel<<<dim3(8, 8, RZ), 256, 0, stream>>>(W1, root1, wz1);
    convw9_kernel<<<dim3(8, 8, RZ), 256, 0, stream>>>(W2, root2, wz2);

    const int NGB = (N_NODES + 127) / 128;   // 391
    const int NAB = (N_NODES + 7) / 8;       // 6250

    // ---- layer 1: transform then aggregate ----
    transform_gemm<<<NGB, 256, 0, stream>>>(xb, wz1, z);
    agg2_kernel<<<NAB, 256, 0, stream>>>(z, zw, off, b1, h1);

    // ---- layer 2 ----
    transform_gemm<<<NGB, 256, 0, stream>>>(h1, wz2, z);
    agg2_kernel<<<NAB, 256, 0, stream>>>(z, zw, off, b2, h2);

    // ---- pool (two-stage, no atomics) + classify ----
    pool1_kernel<<<dim3(G_GRAPHS, PCHUNK), 256, 0, stream>>>(h2, batch, partial);
    pool2_kernel<<<G_GRAPHS, 128, 0, stream>>>(partial, batch, gmean);
    final_kernel<<<G_GRAPHS, HIDF, 0, stream>>>(gmean, lin_w, lin_b, out);

    (void)in_sizes; (void)n_in; (void)out_size; (void)ws_size;
}